// Round 6
// baseline (456.317 us; speedup 1.0000x reference)
//
#include <hip/hip_runtime.h>

#define EPS_BN 1e-5f
#define NEG_SLOPE 0.01f

// ---- bf16x2 pack/unpack (RNE) ----
__device__ __forceinline__ uint32_t pack2_bf16(float x, float y) {
    uint32_t ux = __float_as_uint(x);
    uint32_t uy = __float_as_uint(y);
    ux = (ux + 0x7fffu + ((ux >> 16) & 1u)) >> 16;
    uy = (uy + 0x7fffu + ((uy >> 16) & 1u)) >> 16;
    return (uy << 16) | (ux & 0xffffu);
}
__device__ __forceinline__ float bf_lo(uint32_t p) { return __uint_as_float(p << 16); }
__device__ __forceinline__ float bf_hi(uint32_t p) { return __uint_as_float(p & 0xffff0000u); }

// ---- degree count ----
__global__ void deg_count_kernel(const int* __restrict__ dst, int* __restrict__ cnt, int E) {
    int e = blockIdx.x * blockDim.x + threadIdx.x;
    if (e < E) atomicAdd(&cnt[dst[e]], 1);
}

// ---- block scan of cnt -> rowptr; emits dinv and xs = x*dinv (float4, pad) ----
__global__ void scan_block_kernel(const int* __restrict__ cnt, int* __restrict__ rowptr,
                                  int* __restrict__ bsum, float* __restrict__ dinv,
                                  const float* __restrict__ x, float4* __restrict__ xs, int N) {
    __shared__ int s[256];
    int i = blockIdx.x * 256 + threadIdx.x;
    int v = (i < N) ? cnt[i] : 0;
    if (i < N) {
        float di = rsqrtf((float)(v + 1));              // +1 self-loop, always > 0
        dinv[i] = di;
        const float* xr = x + (size_t)i * 3;
        xs[i] = make_float4(xr[0] * di, xr[1] * di, xr[2] * di, 0.f);
    }
    s[threadIdx.x] = v;
    __syncthreads();
    for (int off = 1; off < 256; off <<= 1) {
        int t = (threadIdx.x >= off) ? s[threadIdx.x - off] : 0;
        __syncthreads();
        s[threadIdx.x] += t;
        __syncthreads();
    }
    if (i < N) rowptr[i] = s[threadIdx.x] - v;          // exclusive
    if (threadIdx.x == 255) bsum[blockIdx.x] = s[255];
}

// ---- single-block chunked scan of block sums ----
__global__ void scan_bsum_kernel(int* __restrict__ bsum, int nb) {
    __shared__ int s[512];
    __shared__ int carry;
    if (threadIdx.x == 0) carry = 0;
    __syncthreads();
    for (int base = 0; base < nb; base += 512) {
        int i = base + threadIdx.x;
        int v = (i < nb) ? bsum[i] : 0;
        s[threadIdx.x] = v;
        __syncthreads();
        for (int off = 1; off < 512; off <<= 1) {
            int t = (threadIdx.x >= off) ? s[threadIdx.x - off] : 0;
            __syncthreads();
            s[threadIdx.x] += t;
            __syncthreads();
        }
        int c = carry;
        if (i < nb) bsum[i] = s[threadIdx.x] - v + c;
        __syncthreads();
        if (threadIdx.x == 0) carry = c + s[511];
        __syncthreads();
    }
}

// ---- propagate block offsets; also zero out/gcnt ----
__global__ void scan_add_kernel(int* __restrict__ rowptr, const int* __restrict__ bsum, int N,
                                float* __restrict__ out, float* __restrict__ gcnt, int G) {
    int i = blockIdx.x * 256 + threadIdx.x;
    if (i < N) rowptr[i] += bsum[blockIdx.x];
    if (i < G * 32) out[i] = 0.f;
    if (i < G) gcnt[i] = 0.f;
}

// ---- phase A: stage edges into 32-node buckets (append-dense writes) ----
__global__ void stage_kernel(const int* __restrict__ src, const int* __restrict__ dst,
                             const int* __restrict__ rowptr, int* __restrict__ sc,
                             int2* __restrict__ staged, int E) {
    int e = blockIdx.x * blockDim.x + threadIdx.x;
    if (e >= E) return;
    int s = src[e], d = dst[e];
    int pos = atomicAdd(&sc[d >> 5], 1);
    int base = rowptr[d & ~31];                          // bucket's edge base (L1-hot)
    staged[base + pos] = make_int2(s, d);
}

// ---- phase B: per-bucket exact CSR fill (LDS cursors) + layer-1 x-aggregation ----
__global__ void fill_agg_kernel(const int2* __restrict__ staged, const int* __restrict__ rowptr,
                                const float4* __restrict__ xs, const float* __restrict__ dinv,
                                int* __restrict__ eidx, float4* __restrict__ agg1, int N, int E) {
    __shared__ int cur[32];
    __shared__ int myrow[32];
    __shared__ float acc[32][3];
    int node0 = blockIdx.x << 5;
    int nn = min(32, N - node0);
    if (threadIdx.x < nn) {
        myrow[threadIdx.x] = rowptr[node0 + threadIdx.x];
        cur[threadIdx.x] = 0;
        acc[threadIdx.x][0] = 0.f; acc[threadIdx.x][1] = 0.f; acc[threadIdx.x][2] = 0.f;
    }
    __syncthreads();
    int base = myrow[0];
    int end = (node0 + 32 >= N) ? E : rowptr[node0 + 32];
    for (int t = base + threadIdx.x; t < end; t += blockDim.x) {
        int2 rec = staged[t];
        int local = rec.y - node0;
        int pos = atomicAdd(&cur[local], 1);
        eidx[myrow[local] + pos] = rec.x;               // writes within ~1.6KB range
        float4 xv = xs[rec.x];
        atomicAdd(&acc[local][0], xv.x);
        atomicAdd(&acc[local][1], xv.y);
        atomicAdd(&acc[local][2], xv.z);
    }
    __syncthreads();
    if (threadIdx.x < nn) {
        int node = node0 + threadIdx.x;
        float4 xself = xs[node];
        float di = dinv[node];
        agg1[node] = make_float4((acc[threadIdx.x][0] + xself.x) * di,
                                 (acc[threadIdx.x][1] + xself.y) * di,
                                 (acc[threadIdx.x][2] + xself.z) * di, 0.f);
    }
}

// ---- GEMM1 (3->64) + bias + BN + LeakyReLU fused, fp32 out ----
__global__ void gemm1_bn_kernel(const float4* __restrict__ agg, const float* __restrict__ W,
                                const float* __restrict__ b, const float* __restrict__ gamma,
                                const float* __restrict__ beta, const float* __restrict__ rm,
                                const float* __restrict__ rv, float* __restrict__ h, int N) {
    __shared__ float sW[3 * 64];
    __shared__ float sScale[64], sShift[64];
    if (threadIdx.x < 3 * 64) sW[threadIdx.x] = W[threadIdx.x];
    if (threadIdx.x < 64) {
        int f = threadIdx.x;
        float sc = rsqrtf(rv[f] + EPS_BN) * gamma[f];
        sScale[f] = sc;
        sShift[f] = (b[f] - rm[f]) * sc + beta[f];
    }
    __syncthreads();
    int node = blockIdx.x * 8 + (int)(threadIdx.x >> 5);
    if (node >= N) return;
    int f0 = (threadIdx.x & 31) * 2, f1 = f0 + 1;
    float4 av = agg[node];
    float a0 = av.x * sW[f0] + av.y * sW[64 + f0] + av.z * sW[128 + f0];
    float a1 = av.x * sW[f1] + av.y * sW[64 + f1] + av.z * sW[128 + f1];
    float y0 = a0 * sScale[f0] + sShift[f0];
    float y1 = a1 * sScale[f1] + sShift[f1];
    float2 o;
    o.x = (y0 >= 0.f) ? y0 : NEG_SLOPE * y0;
    o.y = (y1 >= 0.f) ? y1 : NEG_SLOPE * y1;
    *(float2*)(h + (size_t)node * 64 + f0) = o;
}

// ---- dense GEMM + dinv row-scale + bf16 pack: Tp[n] = (H[n]@W)*dinv[n] ----
template <int FIN, int FOUT>
__global__ void gemm_pack_scale_kernel(const float* __restrict__ H, const float* __restrict__ W,
                                       const float* __restrict__ dinv, uint32_t* __restrict__ Tp,
                                       int N) {
    constexpr int TPN = FOUT / 2;
    constexpr int NPB = 256 / TPN;
    __shared__ float sW[FIN * FOUT];
    for (int i = threadIdx.x; i < FIN * FOUT; i += 256) sW[i] = W[i];
    __syncthreads();
    int node = blockIdx.x * NPB + (int)(threadIdx.x / TPN);
    int f2 = threadIdx.x % TPN;
    if (node >= N) return;
    const float* h = H + (size_t)node * FIN;
    const float2* w2 = (const float2*)sW + f2;
    float a0 = 0.f, a1 = 0.f;
    for (int k = 0; k + 4 <= FIN; k += 4) {
        float4 hv = *(const float4*)(h + k);
        float2 w;
        w = w2[(k + 0) * TPN]; a0 = fmaf(hv.x, w.x, a0); a1 = fmaf(hv.x, w.y, a1);
        w = w2[(k + 1) * TPN]; a0 = fmaf(hv.y, w.x, a0); a1 = fmaf(hv.y, w.y, a1);
        w = w2[(k + 2) * TPN]; a0 = fmaf(hv.z, w.x, a0); a1 = fmaf(hv.z, w.y, a1);
        w = w2[(k + 3) * TPN]; a0 = fmaf(hv.w, w.x, a0); a1 = fmaf(hv.w, w.y, a1);
    }
    float di = dinv[node];
    Tp[(size_t)node * TPN + f2] = pack2_bf16(a0 * di, a1 * di);
}

// ---- CSR gather (scaled bf16 rows, 4B edge records) + BN + LeakyReLU ----
template <int F>
__global__ void gather_fuse_kernel(const uint32_t* __restrict__ Tp, const int* __restrict__ rowptr,
                                   const int* __restrict__ cnt, const int* __restrict__ eidx,
                                   const float* __restrict__ dinv,
                                   const float* __restrict__ b, const float* __restrict__ gamma,
                                   const float* __restrict__ beta, const float* __restrict__ rm,
                                   const float* __restrict__ rv,
                                   float* __restrict__ h, int N) {
    constexpr int TPN = F / 2;
    int tid = blockIdx.x * blockDim.x + threadIdx.x;
    int node = tid / TPN;
    if (node >= N) return;
    int f2 = tid % TPN;
    int start = rowptr[node];
    int deg = cnt[node];
    uint32_t tself = Tp[(size_t)node * TPN + f2];
    float a0 = bf_lo(tself), a1 = bf_hi(tself);         // self term (rows pre-scaled)
    float c0 = 0.f, c1 = 0.f;
    const int* ep = eidx + start;
    int j = 0;
    for (; j + 2 <= deg; j += 2) {
        int s0 = ep[j], s1 = ep[j + 1];
        uint32_t t0 = Tp[(size_t)s0 * TPN + f2];
        uint32_t t1 = Tp[(size_t)s1 * TPN + f2];
        a0 += bf_lo(t0); a1 += bf_hi(t0);
        c0 += bf_lo(t1); c1 += bf_hi(t1);
    }
    if (j < deg) {
        uint32_t t0 = Tp[(size_t)ep[j] * TPN + f2];
        a0 += bf_lo(t0); a1 += bf_hi(t0);
    }
    float di = dinv[node];
    int f0 = 2 * f2, f1 = f0 + 1;
    float sc0 = rsqrtf(rv[f0] + EPS_BN) * gamma[f0];
    float sc1 = rsqrtf(rv[f1] + EPS_BN) * gamma[f1];
    float y0 = (a0 + c0) * di * sc0 + (b[f0] - rm[f0]) * sc0 + beta[f0];
    float y1 = (a1 + c1) * di * sc1 + (b[f1] - rm[f1]) * sc1 + beta[f1];
    float2 o;
    o.x = (y0 >= 0.f) ? y0 : NEG_SLOPE * y0;
    o.y = (y1 >= 0.f) ? y1 : NEG_SLOPE * y1;
    *(float2*)(h + (size_t)node * F + f0) = o;
}

// ---- mean pool: batch sorted -> register-accumulate, flush on graph change ----
#define POOL_ROWS 128
__global__ void pool_kernel2(const float* __restrict__ h, const int* __restrict__ batch,
                             float* __restrict__ out, float* __restrict__ gcnt, int N) {
    int f = threadIdx.x & 31;
    int rg = threadIdx.x >> 5;
    int n0 = blockIdx.x * POOL_ROWS;
    float acc = 0.f;
    int cnt = 0, gcur = -1;
    for (int r = rg; r < POOL_ROWS; r += 8) {
        int node = n0 + r;
        if (node >= N) break;
        int g = batch[node];
        if (g != gcur) {
            if (gcur >= 0) {
                atomicAdd(&out[(gcur << 5) + f], acc);
                if (f == 0) atomicAdd(&gcnt[gcur], (float)cnt);
            }
            gcur = g; acc = 0.f; cnt = 0;
        }
        acc += h[(size_t)node * 32 + f];
        cnt++;
    }
    if (gcur >= 0) {
        atomicAdd(&out[(gcur << 5) + f], acc);
        if (f == 0) atomicAdd(&gcnt[gcur], (float)cnt);
    }
}

__global__ void pool_div_kernel(float* __restrict__ out, const float* __restrict__ gcnt, int G) {
    int tid = blockIdx.x * blockDim.x + threadIdx.x;
    if (tid < (G << 5)) out[tid] /= fmaxf(gcnt[tid >> 5], 1.0f);
}

extern "C" void kernel_launch(void* const* d_in, const int* in_sizes, int n_in,
                              void* d_out, int out_size, void* d_ws, size_t ws_size,
                              hipStream_t stream) {
    const float* x   = (const float*)d_in[0];
    const float* W1  = (const float*)d_in[1];
    const float* b1  = (const float*)d_in[2];
    const float* g1  = (const float*)d_in[3];
    const float* be1 = (const float*)d_in[4];
    const float* rm1 = (const float*)d_in[5];
    const float* rv1 = (const float*)d_in[6];
    const float* W2  = (const float*)d_in[7];
    const float* b2  = (const float*)d_in[8];
    const float* g2  = (const float*)d_in[9];
    const float* be2 = (const float*)d_in[10];
    const float* rm2 = (const float*)d_in[11];
    const float* rv2 = (const float*)d_in[12];
    const float* W3  = (const float*)d_in[13];
    const float* b3  = (const float*)d_in[14];
    const float* g3  = (const float*)d_in[15];
    const float* be3 = (const float*)d_in[16];
    const float* rm3 = (const float*)d_in[17];
    const float* rv3 = (const float*)d_in[18];
    const int* ei    = (const int*)d_in[19];
    const int* batch = (const int*)d_in[20];

    const int N = in_sizes[0] / 3;
    const int E = in_sizes[19] / 2;
    const int G = out_size / 32;
    const int* src = ei;
    const int* dst = ei + E;

    const int B = 256;
    const int nScanBlocks = (N + 255) / 256;
    const int NB = (N + 31) / 32;                        // 32-node buckets

    // workspace layout
    int*      cnt    = (int*)d_ws;                       // N
    int*      sc     = cnt + N;                          // bucket stage cursors (pad 8192)
    float*    dinv   = (float*)(sc + 8192);              // N
    int*      rowptr = (int*)(dinv + N);                 // N
    int*      bsum   = rowptr + N;                       // 1024 pad
    int*      eidx   = bsum + 1024;                      // E ints
    float4*   xs     = (float4*)(((uintptr_t)(eidx + E) + 15) & ~(uintptr_t)15);  // N float4
    float4*   agg1   = xs + N;                           // N float4
    uint32_t* Tp     = (uint32_t*)(agg1 + N);            // N*32 (bf16x2, max FOUT=64)
    float*    hbuf   = (float*)(Tp + (size_t)N * 32);    // N*64
    float*    gcnt   = hbuf + (size_t)N * 64;            // G
    int2*     staged = (int2*)hbuf;                      // alias: dead before hbuf written
    float*    out    = (float*)d_out;

    // ---- degrees (also zero bucket cursors in same memset) ----
    hipMemsetAsync(cnt, 0, ((size_t)N + 8192) * 4, stream);
    deg_count_kernel<<<(E + B - 1) / B, B, 0, stream>>>(dst, cnt, E);

    // ---- CSR scan + dinv + xs; out/gcnt zero fused in ----
    scan_block_kernel<<<nScanBlocks, 256, 0, stream>>>(cnt, rowptr, bsum, dinv, x, xs, N);
    scan_bsum_kernel<<<1, 512, 0, stream>>>(bsum, nScanBlocks);
    scan_add_kernel<<<nScanBlocks, 256, 0, stream>>>(rowptr, bsum, N, out, gcnt, G);

    // ---- two-phase bucketed fill; phase B also does layer-1 aggregation ----
    stage_kernel<<<(E + B - 1) / B, B, 0, stream>>>(src, dst, rowptr, sc, staged, E);
    fill_agg_kernel<<<NB, 256, 0, stream>>>(staged, rowptr, xs, dinv, eidx, agg1, N, E);

    // ---- layer 1 GEMM (3->64) + BN fused ----
    gemm1_bn_kernel<<<(N + 7) / 8, 256, 0, stream>>>(agg1, W1, b1, g1, be1, rm1, rv1, hbuf, N);

    // ---- layer 2 ----
    gemm_pack_scale_kernel<64, 64><<<(N + 7) / 8, 256, 0, stream>>>(hbuf, W2, dinv, Tp, N);
    gather_fuse_kernel<64><<<(int)(((size_t)N * 32 + B - 1) / B), B, 0, stream>>>(
        Tp, rowptr, cnt, eidx, dinv, b2, g2, be2, rm2, rv2, hbuf, N);

    // ---- layer 3 ----
    gemm_pack_scale_kernel<64, 32><<<(N + 15) / 16, 256, 0, stream>>>(hbuf, W3, dinv, Tp, N);
    gather_fuse_kernel<32><<<(int)(((size_t)N * 16 + B - 1) / B), B, 0, stream>>>(
        Tp, rowptr, cnt, eidx, dinv, b3, g3, be3, rm3, rv3, hbuf, N);

    // ---- mean pool ----
    pool_kernel2<<<(N + POOL_ROWS - 1) / POOL_ROWS, 256, 0, stream>>>(hbuf, batch, out, gcnt, N);
    pool_div_kernel<<<(G * 32 + B - 1) / B, B, 0, stream>>>(out, gcnt, G);
}

// Round 7
// 370.559 us; speedup vs baseline: 1.2314x; 1.2314x over previous
//
#include <hip/hip_runtime.h>

#define EPS_BN 1e-5f
#define NEG_SLOPE 0.01f

#define BINSHIFT 9                 // 512 nodes per bin
#define NBINS_MAX 256
#define BUFCAP 24                  // LDS records per bin in stage kernel

// ---- bf16x2 pack/unpack (RNE) ----
__device__ __forceinline__ uint32_t pack2_bf16(float x, float y) {
    uint32_t ux = __float_as_uint(x);
    uint32_t uy = __float_as_uint(y);
    ux = (ux + 0x7fffu + ((ux >> 16) & 1u)) >> 16;
    uy = (uy + 0x7fffu + ((uy >> 16) & 1u)) >> 16;
    return (uy << 16) | (ux & 0xffffu);
}
__device__ __forceinline__ float bf_lo(uint32_t p) { return __uint_as_float(p << 16); }
__device__ __forceinline__ float bf_hi(uint32_t p) { return __uint_as_float(p & 0xffff0000u); }

// ---- phase A: multisplit stage. Each line of `staged` is written by ONE thread ----
__global__ void stage_ms_kernel(const int* __restrict__ src, const int* __restrict__ dst,
                                int* __restrict__ gcur, int2* __restrict__ staged,
                                int cap, int nbins, int E, int chunk) {
    __shared__ int2 bbuf[NBINS_MAX][BUFCAP];
    __shared__ int bcnt[NBINS_MAX];
    for (int i = threadIdx.x; i < nbins; i += 256) bcnt[i] = 0;
    __syncthreads();
    int e0 = blockIdx.x * chunk;
    int e1 = min(e0 + chunk, E);
    for (int base = e0; base < e1; base += 256) {
        int e = base + threadIdx.x;
        if (e < e1) {
            int s = src[e], d = dst[e];
            int bin = d >> BINSHIFT;
            int pos = atomicAdd(&bcnt[bin], 1);
            if (pos < BUFCAP) {
                bbuf[bin][pos] = make_int2(s, d);
            } else {                                   // rare overflow: direct global append
                atomicSub(&bcnt[bin], 1);
                int gp = atomicAdd(&gcur[bin], 1);
                staged[(size_t)bin * cap + gp] = make_int2(s, d);
            }
        }
        __syncthreads();
        // flush full 16-record (128B) chunks; thread t owns bin t
        for (int b = threadIdx.x; b < nbins; b += 256) {
            int c = bcnt[b];
            int nf = c & ~15;
            if (nf > 0) {
                int gp = atomicAdd(&gcur[b], nf);
                int2* o = staged + (size_t)b * cap + gp;
                for (int i = 0; i < nf; ++i) o[i] = bbuf[b][i];
                for (int i = 0; i < c - nf; ++i) bbuf[b][i] = bbuf[b][nf + i];
                bcnt[b] = c - nf;
            }
        }
        __syncthreads();
    }
    for (int b = threadIdx.x; b < nbins; b += 256) {   // final drain (<16 recs/bin)
        int c = bcnt[b];
        if (c > 0) {
            int gp = atomicAdd(&gcur[b], c);
            int2* o = staged + (size_t)b * cap + gp;
            for (int i = 0; i < c; ++i) o[i] = bbuf[b][i];
        }
    }
}

// ---- exclusive scan of per-bin counts -> binbase; also zeros out/gcnt ----
__global__ void binscan_kernel(const int* __restrict__ gcur, int* __restrict__ binbase,
                               int nbins, float* __restrict__ out, float* __restrict__ gcnt,
                               int G) {
    __shared__ int s[256];
    int v = (threadIdx.x < nbins) ? gcur[threadIdx.x] : 0;
    s[threadIdx.x] = v;
    __syncthreads();
    for (int off = 1; off < 256; off <<= 1) {
        int t = (threadIdx.x >= off) ? s[threadIdx.x - off] : 0;
        __syncthreads();
        s[threadIdx.x] += t;
        __syncthreads();
    }
    if (threadIdx.x < nbins) binbase[threadIdx.x] = s[threadIdx.x] - v;
    for (int i = threadIdx.x; i < G * 32; i += 256) out[i] = 0.f;
    for (int i = threadIdx.x; i < G; i += 256) gcnt[i] = 0.f;
}

// ---- phase B: per-bin CSR fill + rowptr/cnt/dinv/xs (replaces deg_count + N-scan) ----
__global__ void fill_csr_kernel(const int2* __restrict__ staged, const int* __restrict__ binbase,
                                const int* __restrict__ gcur, const float* __restrict__ x,
                                int cap, int* __restrict__ rowptr, int* __restrict__ cnt,
                                float* __restrict__ dinv, float4* __restrict__ xs,
                                int* __restrict__ eidx, int N) {
    __shared__ int lcnt[1 << BINSHIFT];
    __shared__ int loff[1 << BINSHIFT];
    int bin = blockIdx.x;
    int node0 = bin << BINSHIFT;
    int nn = min(1 << BINSHIFT, N - node0);
    int nrec = gcur[bin];
    const int2* recs = staged + (size_t)bin * cap;
    for (int i = threadIdx.x; i < nn; i += 256) lcnt[i] = 0;
    __syncthreads();
    for (int t = threadIdx.x; t < nrec; t += 256) atomicAdd(&lcnt[recs[t].y - node0], 1);
    __syncthreads();
    if (threadIdx.x == 0) {                            // serial in-bin scan (196 blocks overlap)
        int acc = 0;
        for (int i = 0; i < nn; ++i) { loff[i] = acc; acc += lcnt[i]; }
    }
    __syncthreads();
    int bb = binbase[bin];
    for (int i = threadIdx.x; i < nn; i += 256) {
        int node = node0 + i;
        rowptr[node] = bb + loff[i];
        cnt[node] = lcnt[i];
        float di = rsqrtf((float)(lcnt[i] + 1));       // +1 self-loop
        dinv[node] = di;
        const float* xr = x + (size_t)node * 3;
        xs[node] = make_float4(xr[0] * di, xr[1] * di, xr[2] * di, 0.f);
        lcnt[i] = 0;                                   // reuse as cursor
    }
    __syncthreads();
    for (int t = threadIdx.x; t < nrec; t += 256) {
        int2 r = recs[t];
        int li = r.y - node0;
        int p = atomicAdd(&lcnt[li], 1);
        eidx[bb + loff[li] + p] = r.x;                 // block-private 24KB range
    }
}

// ---- layer-1 gather on raw features: agg[n] = dinv[n]*(sum xs[s] + xs[n]) ----
__global__ void gather_x_kernel(const float* __restrict__ xs, const int* __restrict__ rowptr,
                                const int* __restrict__ cnt, const int* __restrict__ eidx,
                                const float* __restrict__ dinv, float* __restrict__ agg, int N) {
    int tid = blockIdx.x * blockDim.x + threadIdx.x;
    int node = tid >> 2;
    if (node >= N) return;
    int f = tid & 3;
    int start = rowptr[node];
    int deg = cnt[node];
    float acc = xs[4 * (size_t)node + f];
    const int* ep = eidx + start;
    int j = 0;
    float acc2 = 0.f;
    for (; j + 2 <= deg; j += 2) {
        int s0 = ep[j], s1 = ep[j + 1];
        acc  += xs[4 * (size_t)s0 + f];
        acc2 += xs[4 * (size_t)s1 + f];
    }
    if (j < deg) acc += xs[4 * (size_t)ep[j] + f];
    agg[4 * (size_t)node + f] = (acc + acc2) * dinv[node];
}

// ---- GEMM1 (3->64) + bias + BN + LeakyReLU fused ----
__global__ void gemm1_bn_kernel(const float4* __restrict__ agg, const float* __restrict__ W,
                                const float* __restrict__ b, const float* __restrict__ gamma,
                                const float* __restrict__ beta, const float* __restrict__ rm,
                                const float* __restrict__ rv, float* __restrict__ h, int N) {
    __shared__ float sW[3 * 64];
    __shared__ float sScale[64], sShift[64];
    if (threadIdx.x < 3 * 64) sW[threadIdx.x] = W[threadIdx.x];
    if (threadIdx.x < 64) {
        int f = threadIdx.x;
        float sc = rsqrtf(rv[f] + EPS_BN) * gamma[f];
        sScale[f] = sc;
        sShift[f] = (b[f] - rm[f]) * sc + beta[f];
    }
    __syncthreads();
    int node = blockIdx.x * 8 + (int)(threadIdx.x >> 5);
    if (node >= N) return;
    int f0 = (threadIdx.x & 31) * 2, f1 = f0 + 1;
    float4 av = agg[node];
    float a0 = av.x * sW[f0] + av.y * sW[64 + f0] + av.z * sW[128 + f0];
    float a1 = av.x * sW[f1] + av.y * sW[64 + f1] + av.z * sW[128 + f1];
    float y0 = a0 * sScale[f0] + sShift[f0];
    float y1 = a1 * sScale[f1] + sShift[f1];
    float2 o;
    o.x = (y0 >= 0.f) ? y0 : NEG_SLOPE * y0;
    o.y = (y1 >= 0.f) ? y1 : NEG_SLOPE * y1;
    *(float2*)(h + (size_t)node * 64 + f0) = o;
}

// ---- dense GEMM + dinv row-scale + bf16 pack: Tp[n] = (H[n]@W)*dinv[n] ----
template <int FIN, int FOUT>
__global__ void gemm_pack_scale_kernel(const float* __restrict__ H, const float* __restrict__ W,
                                       const float* __restrict__ dinv, uint32_t* __restrict__ Tp,
                                       int N) {
    constexpr int TPN = FOUT / 2;
    constexpr int NPB = 256 / TPN;
    __shared__ float sW[FIN * FOUT];
    for (int i = threadIdx.x; i < FIN * FOUT; i += 256) sW[i] = W[i];
    __syncthreads();
    int node = blockIdx.x * NPB + (int)(threadIdx.x / TPN);
    int f2 = threadIdx.x % TPN;
    if (node >= N) return;
    const float* h = H + (size_t)node * FIN;
    const float2* w2 = (const float2*)sW + f2;
    float a0 = 0.f, a1 = 0.f;
    for (int k = 0; k + 4 <= FIN; k += 4) {
        float4 hv = *(const float4*)(h + k);
        float2 w;
        w = w2[(k + 0) * TPN]; a0 = fmaf(hv.x, w.x, a0); a1 = fmaf(hv.x, w.y, a1);
        w = w2[(k + 1) * TPN]; a0 = fmaf(hv.y, w.x, a0); a1 = fmaf(hv.y, w.y, a1);
        w = w2[(k + 2) * TPN]; a0 = fmaf(hv.z, w.x, a0); a1 = fmaf(hv.z, w.y, a1);
        w = w2[(k + 3) * TPN]; a0 = fmaf(hv.w, w.x, a0); a1 = fmaf(hv.w, w.y, a1);
    }
    float di = dinv[node];
    Tp[(size_t)node * TPN + f2] = pack2_bf16(a0 * di, a1 * di);
}

// ---- CSR gather (scaled bf16 rows, 4B records) + BN + LeakyReLU ----
template <int F>
__global__ void gather_fuse_kernel(const uint32_t* __restrict__ Tp, const int* __restrict__ rowptr,
                                   const int* __restrict__ cnt, const int* __restrict__ eidx,
                                   const float* __restrict__ dinv,
                                   const float* __restrict__ b, const float* __restrict__ gamma,
                                   const float* __restrict__ beta, const float* __restrict__ rm,
                                   const float* __restrict__ rv,
                                   float* __restrict__ h, int N) {
    constexpr int TPN = F / 2;
    int tid = blockIdx.x * blockDim.x + threadIdx.x;
    int node = tid / TPN;
    if (node >= N) return;
    int f2 = tid % TPN;
    int start = rowptr[node];
    int deg = cnt[node];
    uint32_t tself = Tp[(size_t)node * TPN + f2];
    float a0 = bf_lo(tself), a1 = bf_hi(tself);
    float c0 = 0.f, c1 = 0.f;
    const int* ep = eidx + start;
    int j = 0;
    for (; j + 2 <= deg; j += 2) {
        int s0 = ep[j], s1 = ep[j + 1];
        uint32_t t0 = Tp[(size_t)s0 * TPN + f2];
        uint32_t t1 = Tp[(size_t)s1 * TPN + f2];
        a0 += bf_lo(t0); a1 += bf_hi(t0);
        c0 += bf_lo(t1); c1 += bf_hi(t1);
    }
    if (j < deg) {
        uint32_t t0 = Tp[(size_t)ep[j] * TPN + f2];
        a0 += bf_lo(t0); a1 += bf_hi(t0);
    }
    float di = dinv[node];
    int f0 = 2 * f2, f1 = f0 + 1;
    float sc0 = rsqrtf(rv[f0] + EPS_BN) * gamma[f0];
    float sc1 = rsqrtf(rv[f1] + EPS_BN) * gamma[f1];
    float y0 = (a0 + c0) * di * sc0 + (b[f0] - rm[f0]) * sc0 + beta[f0];
    float y1 = (a1 + c1) * di * sc1 + (b[f1] - rm[f1]) * sc1 + beta[f1];
    float2 o;
    o.x = (y0 >= 0.f) ? y0 : NEG_SLOPE * y0;
    o.y = (y1 >= 0.f) ? y1 : NEG_SLOPE * y1;
    *(float2*)(h + (size_t)node * F + f0) = o;
}

// ---- mean pool: batch sorted -> register-accumulate, flush on graph change ----
#define POOL_ROWS 128
__global__ void pool_kernel2(const float* __restrict__ h, const int* __restrict__ batch,
                             float* __restrict__ out, float* __restrict__ gcnt, int N) {
    int f = threadIdx.x & 31;
    int rg = threadIdx.x >> 5;
    int n0 = blockIdx.x * POOL_ROWS;
    float acc = 0.f;
    int cnt = 0, gcur = -1;
    for (int r = rg; r < POOL_ROWS; r += 8) {
        int node = n0 + r;
        if (node >= N) break;
        int g = batch[node];
        if (g != gcur) {
            if (gcur >= 0) {
                atomicAdd(&out[(gcur << 5) + f], acc);
                if (f == 0) atomicAdd(&gcnt[gcur], (float)cnt);
            }
            gcur = g; acc = 0.f; cnt = 0;
        }
        acc += h[(size_t)node * 32 + f];
        cnt++;
    }
    if (gcur >= 0) {
        atomicAdd(&out[(gcur << 5) + f], acc);
        if (f == 0) atomicAdd(&gcnt[gcur], (float)cnt);
    }
}

__global__ void pool_div_kernel(float* __restrict__ out, const float* __restrict__ gcnt, int G) {
    int tid = blockIdx.x * blockDim.x + threadIdx.x;
    if (tid < (G << 5)) out[tid] /= fmaxf(gcnt[tid >> 5], 1.0f);
}

extern "C" void kernel_launch(void* const* d_in, const int* in_sizes, int n_in,
                              void* d_out, int out_size, void* d_ws, size_t ws_size,
                              hipStream_t stream) {
    const float* x   = (const float*)d_in[0];
    const float* W1  = (const float*)d_in[1];
    const float* b1  = (const float*)d_in[2];
    const float* g1  = (const float*)d_in[3];
    const float* be1 = (const float*)d_in[4];
    const float* rm1 = (const float*)d_in[5];
    const float* rv1 = (const float*)d_in[6];
    const float* W2  = (const float*)d_in[7];
    const float* b2  = (const float*)d_in[8];
    const float* g2  = (const float*)d_in[9];
    const float* be2 = (const float*)d_in[10];
    const float* rm2 = (const float*)d_in[11];
    const float* rv2 = (const float*)d_in[12];
    const float* W3  = (const float*)d_in[13];
    const float* b3  = (const float*)d_in[14];
    const float* g3  = (const float*)d_in[15];
    const float* be3 = (const float*)d_in[16];
    const float* rm3 = (const float*)d_in[17];
    const float* rv3 = (const float*)d_in[18];
    const int* ei    = (const int*)d_in[19];
    const int* batch = (const int*)d_in[20];

    const int N = in_sizes[0] / 3;
    const int E = in_sizes[19] / 2;
    const int G = out_size / 32;
    const int* src = ei;
    const int* dst = ei + E;

    const int B = 256;
    const int nbins = (N + (1 << BINSHIFT) - 1) >> BINSHIFT;          // 196 for N=100k
    const int cap = (((E / nbins) * 3) / 2 + 15) & ~15;               // 1.5x mean, 16-aligned
    const int STAGE_BLOCKS = 128;
    const int chunk = (E + STAGE_BLOCKS - 1) / STAGE_BLOCKS;

    // workspace layout
    int*      gcur    = (int*)d_ws;                       // NBINS_MAX
    int*      binbase = gcur + NBINS_MAX;                 // NBINS_MAX
    int*      cnt     = binbase + NBINS_MAX;              // N
    float*    dinv    = (float*)(cnt + N);                // N
    int*      rowptr  = (int*)(dinv + N);                 // N
    int*      eidx    = rowptr + N;                       // E
    float4*   xs      = (float4*)(((uintptr_t)(eidx + E) + 15) & ~(uintptr_t)15);  // N
    float4*   agg1    = xs + N;                           // N
    uint32_t* Tp      = (uint32_t*)(agg1 + N);            // N*32
    float*    hbuf    = (float*)(Tp + (size_t)N * 32);    // N*64
    float*    gcnt    = hbuf + (size_t)N * 64;            // G
    int2*     staged  = (int2*)hbuf;                      // alias: dead before hbuf written
    float*    out     = (float*)d_out;

    // ---- CSR build: multisplit stage -> bin scan -> per-bin fill ----
    hipMemsetAsync(gcur, 0, NBINS_MAX * 4, stream);
    stage_ms_kernel<<<STAGE_BLOCKS, 256, 0, stream>>>(src, dst, gcur, staged, cap, nbins, E, chunk);
    binscan_kernel<<<1, 256, 0, stream>>>(gcur, binbase, nbins, out, gcnt, G);
    fill_csr_kernel<<<nbins, 256, 0, stream>>>(staged, binbase, gcur, x, cap,
                                               rowptr, cnt, dinv, xs, eidx, N);

    // ---- layer 1 (aggregate-first): agg1 = A_norm @ x ; GEMM+BN fused ----
    gather_x_kernel<<<(int)(((size_t)N * 4 + B - 1) / B), B, 0, stream>>>(
        (const float*)xs, rowptr, cnt, eidx, dinv, (float*)agg1, N);
    gemm1_bn_kernel<<<(N + 7) / 8, 256, 0, stream>>>(agg1, W1, b1, g1, be1, rm1, rv1, hbuf, N);

    // ---- layer 2 ----
    gemm_pack_scale_kernel<64, 64><<<(N + 7) / 8, 256, 0, stream>>>(hbuf, W2, dinv, Tp, N);
    gather_fuse_kernel<64><<<(int)(((size_t)N * 32 + B - 1) / B), B, 0, stream>>>(
        Tp, rowptr, cnt, eidx, dinv, b2, g2, be2, rm2, rv2, hbuf, N);

    // ---- layer 3 ----
    gemm_pack_scale_kernel<64, 32><<<(N + 15) / 16, 256, 0, stream>>>(hbuf, W3, dinv, Tp, N);
    gather_fuse_kernel<32><<<(int)(((size_t)N * 16 + B - 1) / B), B, 0, stream>>>(
        Tp, rowptr, cnt, eidx, dinv, b3, g3, be3, rm3, rv3, hbuf, N);

    // ---- mean pool ----
    pool_kernel2<<<(N + POOL_ROWS - 1) / POOL_ROWS, 256, 0, stream>>>(hbuf, batch, out, gcnt, N);
    pool_div_kernel<<<(G * 32 + B - 1) / B, B, 0, stream>>>(out, gcnt, G);
}

// Round 8
// 357.630 us; speedup vs baseline: 1.2759x; 1.0362x over previous
//
#include <hip/hip_runtime.h>

#define EPS_BN 1e-5f
#define NEG_SLOPE 0.01f

#define BINSHIFT 9                 // 512 nodes per bin
#define NBINS_LDS 200              // supports N up to 102400
#define BUFCAP 24                  // LDS records per (block,bin)
#define GSTRIDE 16                 // gcur padding: one counter per 64B line

// ---- bf16x2 pack/unpack (RNE) ----
__device__ __forceinline__ uint32_t pack2_bf16(float x, float y) {
    uint32_t ux = __float_as_uint(x);
    uint32_t uy = __float_as_uint(y);
    ux = (ux + 0x7fffu + ((ux >> 16) & 1u)) >> 16;
    uy = (uy + 0x7fffu + ((uy >> 16) & 1u)) >> 16;
    return (uy << 16) | (ux & 0xffffu);
}
__device__ __forceinline__ float bf_lo(uint32_t p) { return __uint_as_float(p << 16); }
__device__ __forceinline__ float bf_hi(uint32_t p) { return __uint_as_float(p & 0xffff0000u); }

// ---- phase A: LDS multisplit, cooperative 16-lane drain (no in-loop flush) ----
__global__ void stage_ms_kernel(const int* __restrict__ src, const int* __restrict__ dst,
                                int* __restrict__ gcur, int2* __restrict__ staged,
                                int cap, int nbins, int E, int chunk) {
    __shared__ int2 bbuf[NBINS_LDS][BUFCAP];
    __shared__ int bcnt[NBINS_LDS];
    for (int i = threadIdx.x; i < nbins; i += 256) bcnt[i] = 0;
    __syncthreads();
    int e0 = blockIdx.x * chunk;
    int e1 = min(e0 + chunk, E);
    for (int e = e0 + threadIdx.x; e < e1; e += 256) {
        int s = src[e], d = dst[e];
        int bin = d >> BINSHIFT;
        int pos = atomicAdd(&bcnt[bin], 1);
        if (pos < BUFCAP) {
            bbuf[bin][pos] = make_int2(s, d);
        } else {                                        // rare: direct global append
            int gp = atomicAdd(&gcur[bin * GSTRIDE], 1);
            staged[(size_t)bin * cap + gp] = make_int2(s, d);
        }
    }
    __syncthreads();
    // cooperative drain: 16 groups of 16 lanes; lanes store contiguous records
    int grp = threadIdx.x >> 4, lane = threadIdx.x & 15;
    for (int b = grp; b < nbins; b += 16) {
        int c = min(bcnt[b], BUFCAP);
        if (c == 0) continue;
        int gp = 0;
        if (lane == 0) gp = atomicAdd(&gcur[b * GSTRIDE], c);
        gp = __shfl(gp, 0, 16);
        if (lane < c) staged[(size_t)b * cap + gp + lane] = bbuf[b][lane];
        if (lane + 16 < c) staged[(size_t)b * cap + gp + lane + 16] = bbuf[b][lane + 16];
    }
}

// ---- exclusive scan of per-bin counts -> binbase; also zeros out/gcnt ----
__global__ void binscan_kernel(const int* __restrict__ gcur, int* __restrict__ binbase,
                               int nbins, float* __restrict__ out, float* __restrict__ gcnt,
                               int G) {
    __shared__ int s[256];
    int v = (threadIdx.x < nbins) ? gcur[threadIdx.x * GSTRIDE] : 0;
    s[threadIdx.x] = v;
    __syncthreads();
    for (int off = 1; off < 256; off <<= 1) {
        int t = (threadIdx.x >= off) ? s[threadIdx.x - off] : 0;
        __syncthreads();
        s[threadIdx.x] += t;
        __syncthreads();
    }
    if (threadIdx.x < nbins) binbase[threadIdx.x] = s[threadIdx.x] - v;
    for (int i = threadIdx.x; i < G * 32; i += 256) out[i] = 0.f;
    for (int i = threadIdx.x; i < G; i += 256) gcnt[i] = 0.f;
}

// ---- phase B: per-bin CSR fill + rowptr/cnt/dinv/xs; parallel in-bin scan ----
__global__ void fill_csr_kernel(const int2* __restrict__ staged, const int* __restrict__ binbase,
                                const int* __restrict__ gcur, const float* __restrict__ x,
                                int cap, int* __restrict__ rowptr, int* __restrict__ cnt,
                                float* __restrict__ dinv, float4* __restrict__ xs,
                                int* __restrict__ eidx, int N) {
    __shared__ int lcnt[1 << BINSHIFT];
    __shared__ int loff[1 << BINSHIFT];
    __shared__ int ps[256];
    int bin = blockIdx.x;
    int node0 = bin << BINSHIFT;
    int nn = min(1 << BINSHIFT, N - node0);
    int nrec = gcur[bin * GSTRIDE];
    const int2* recs = staged + (size_t)bin * cap;
    for (int i = threadIdx.x; i < (1 << BINSHIFT); i += 256) lcnt[i] = 0;
    __syncthreads();
    for (int t = threadIdx.x; t < nrec; t += 256) atomicAdd(&lcnt[recs[t].y - node0], 1);
    __syncthreads();
    // parallel exclusive scan of 512 via pair-sums (256 threads)
    int p0 = lcnt[2 * threadIdx.x], p1 = lcnt[2 * threadIdx.x + 1];
    int pv = p0 + p1;
    ps[threadIdx.x] = pv;
    __syncthreads();
    for (int off = 1; off < 256; off <<= 1) {
        int t = (threadIdx.x >= off) ? ps[threadIdx.x - off] : 0;
        __syncthreads();
        ps[threadIdx.x] += t;
        __syncthreads();
    }
    int base = ps[threadIdx.x] - pv;                   // exclusive pair base
    loff[2 * threadIdx.x] = base;
    loff[2 * threadIdx.x + 1] = base + p0;
    __syncthreads();
    int bb = binbase[bin];
    for (int i = threadIdx.x; i < nn; i += 256) {
        int node = node0 + i;
        rowptr[node] = bb + loff[i];
        cnt[node] = lcnt[i];
        float di = rsqrtf((float)(lcnt[i] + 1));       // +1 self-loop
        dinv[node] = di;
        const float* xr = x + (size_t)node * 3;
        xs[node] = make_float4(xr[0] * di, xr[1] * di, xr[2] * di, 0.f);
        lcnt[i] = 0;                                   // reuse as cursor
    }
    __syncthreads();
    for (int t = threadIdx.x; t < nrec; t += 256) {
        int2 r = recs[t];
        int li = r.y - node0;
        int p = atomicAdd(&lcnt[li], 1);
        eidx[bb + loff[li] + p] = r.x;                 // block-private range
    }
}

// ---- fused layer 1: gather xs + (3->64 GEMM) + bias + BN + LeakyReLU ----
// 32 lanes per node: parallel edge loads, shfl reduce, then GEMM epilogue
__global__ void layer1_kernel(const float4* __restrict__ xs, const int* __restrict__ rowptr,
                              const int* __restrict__ cnt, const int* __restrict__ eidx,
                              const float* __restrict__ dinv, const float* __restrict__ W,
                              const float* __restrict__ b, const float* __restrict__ gamma,
                              const float* __restrict__ beta, const float* __restrict__ rm,
                              const float* __restrict__ rv, float* __restrict__ h, int N) {
    __shared__ float sW[3 * 64];
    __shared__ float sScale[64], sShift[64];
    if (threadIdx.x < 3 * 64) sW[threadIdx.x] = W[threadIdx.x];
    if (threadIdx.x < 64) {
        int f = threadIdx.x;
        float sc = rsqrtf(rv[f] + EPS_BN) * gamma[f];
        sScale[f] = sc;
        sShift[f] = (b[f] - rm[f]) * sc + beta[f];
    }
    __syncthreads();
    int node = blockIdx.x * 8 + (int)(threadIdx.x >> 5);
    if (node >= N) return;
    int lane = threadIdx.x & 31;
    int start = rowptr[node], deg = cnt[node];
    float ax = 0.f, ay = 0.f, az = 0.f;
    for (int j = lane; j < deg; j += 32) {
        float4 v = xs[eidx[start + j]];
        ax += v.x; ay += v.y; az += v.z;
    }
    for (int o = 16; o; o >>= 1) {
        ax += __shfl_down(ax, o, 32);
        ay += __shfl_down(ay, o, 32);
        az += __shfl_down(az, o, 32);
    }
    ax = __shfl(ax, 0, 32); ay = __shfl(ay, 0, 32); az = __shfl(az, 0, 32);
    float4 self = xs[node];
    float di = dinv[node];
    float gx = (ax + self.x) * di, gy = (ay + self.y) * di, gz = (az + self.z) * di;
    int f0 = lane * 2, f1 = f0 + 1;
    float a0 = gx * sW[f0] + gy * sW[64 + f0] + gz * sW[128 + f0];
    float a1 = gx * sW[f1] + gy * sW[64 + f1] + gz * sW[128 + f1];
    float y0 = a0 * sScale[f0] + sShift[f0];
    float y1 = a1 * sScale[f1] + sShift[f1];
    float2 o2;
    o2.x = (y0 >= 0.f) ? y0 : NEG_SLOPE * y0;
    o2.y = (y1 >= 0.f) ? y1 : NEG_SLOPE * y1;
    *(float2*)(h + (size_t)node * 64 + f0) = o2;
}

// ---- dense GEMM + dinv row-scale + bf16 pack: Tp[n] = (H[n]@W)*dinv[n] ----
template <int FIN, int FOUT>
__global__ void gemm_pack_scale_kernel(const float* __restrict__ H, const float* __restrict__ W,
                                       const float* __restrict__ dinv, uint32_t* __restrict__ Tp,
                                       int N) {
    constexpr int TPN = FOUT / 2;
    constexpr int NPB = 256 / TPN;
    __shared__ float sW[FIN * FOUT];
    for (int i = threadIdx.x; i < FIN * FOUT; i += 256) sW[i] = W[i];
    __syncthreads();
    int node = blockIdx.x * NPB + (int)(threadIdx.x / TPN);
    int f2 = threadIdx.x % TPN;
    if (node >= N) return;
    const float* h = H + (size_t)node * FIN;
    const float2* w2 = (const float2*)sW + f2;
    float a0 = 0.f, a1 = 0.f;
    for (int k = 0; k + 4 <= FIN; k += 4) {
        float4 hv = *(const float4*)(h + k);
        float2 w;
        w = w2[(k + 0) * TPN]; a0 = fmaf(hv.x, w.x, a0); a1 = fmaf(hv.x, w.y, a1);
        w = w2[(k + 1) * TPN]; a0 = fmaf(hv.y, w.x, a0); a1 = fmaf(hv.y, w.y, a1);
        w = w2[(k + 2) * TPN]; a0 = fmaf(hv.z, w.x, a0); a1 = fmaf(hv.z, w.y, a1);
        w = w2[(k + 3) * TPN]; a0 = fmaf(hv.w, w.x, a0); a1 = fmaf(hv.w, w.y, a1);
    }
    float di = dinv[node];
    Tp[(size_t)node * TPN + f2] = pack2_bf16(a0 * di, a1 * di);
}

// ---- CSR gather (scaled bf16 rows, 4B records) + BN + LeakyReLU ----
template <int F>
__global__ void gather_fuse_kernel(const uint32_t* __restrict__ Tp, const int* __restrict__ rowptr,
                                   const int* __restrict__ cnt, const int* __restrict__ eidx,
                                   const float* __restrict__ dinv,
                                   const float* __restrict__ b, const float* __restrict__ gamma,
                                   const float* __restrict__ beta, const float* __restrict__ rm,
                                   const float* __restrict__ rv,
                                   float* __restrict__ h, int N) {
    constexpr int TPN = F / 2;
    int tid = blockIdx.x * blockDim.x + threadIdx.x;
    int node = tid / TPN;
    if (node >= N) return;
    int f2 = tid % TPN;
    int start = rowptr[node];
    int deg = cnt[node];
    uint32_t tself = Tp[(size_t)node * TPN + f2];
    float a0 = bf_lo(tself), a1 = bf_hi(tself);
    float c0 = 0.f, c1 = 0.f;
    const int* ep = eidx + start;
    int j = 0;
    for (; j + 2 <= deg; j += 2) {
        int s0 = ep[j], s1 = ep[j + 1];
        uint32_t t0 = Tp[(size_t)s0 * TPN + f2];
        uint32_t t1 = Tp[(size_t)s1 * TPN + f2];
        a0 += bf_lo(t0); a1 += bf_hi(t0);
        c0 += bf_lo(t1); c1 += bf_hi(t1);
    }
    if (j < deg) {
        uint32_t t0 = Tp[(size_t)ep[j] * TPN + f2];
        a0 += bf_lo(t0); a1 += bf_hi(t0);
    }
    float di = dinv[node];
    int f0 = 2 * f2, f1 = f0 + 1;
    float sc0 = rsqrtf(rv[f0] + EPS_BN) * gamma[f0];
    float sc1 = rsqrtf(rv[f1] + EPS_BN) * gamma[f1];
    float y0 = (a0 + c0) * di * sc0 + (b[f0] - rm[f0]) * sc0 + beta[f0];
    float y1 = (a1 + c1) * di * sc1 + (b[f1] - rm[f1]) * sc1 + beta[f1];
    float2 o;
    o.x = (y0 >= 0.f) ? y0 : NEG_SLOPE * y0;
    o.y = (y1 >= 0.f) ? y1 : NEG_SLOPE * y1;
    *(float2*)(h + (size_t)node * F + f0) = o;
}

// ---- mean pool: batch sorted -> register-accumulate, flush on graph change ----
#define POOL_ROWS 128
__global__ void pool_kernel2(const float* __restrict__ h, const int* __restrict__ batch,
                             float* __restrict__ out, float* __restrict__ gcnt, int N) {
    int f = threadIdx.x & 31;
    int rg = threadIdx.x >> 5;
    int n0 = blockIdx.x * POOL_ROWS;
    float acc = 0.f;
    int cnt = 0, gcur = -1;
    for (int r = rg; r < POOL_ROWS; r += 8) {
        int node = n0 + r;
        if (node >= N) break;
        int g = batch[node];
        if (g != gcur) {
            if (gcur >= 0) {
                atomicAdd(&out[(gcur << 5) + f], acc);
                if (f == 0) atomicAdd(&gcnt[gcur], (float)cnt);
            }
            gcur = g; acc = 0.f; cnt = 0;
        }
        acc += h[(size_t)node * 32 + f];
        cnt++;
    }
    if (gcur >= 0) {
        atomicAdd(&out[(gcur << 5) + f], acc);
        if (f == 0) atomicAdd(&gcnt[gcur], (float)cnt);
    }
}

__global__ void pool_div_kernel(float* __restrict__ out, const float* __restrict__ gcnt, int G) {
    int tid = blockIdx.x * blockDim.x + threadIdx.x;
    if (tid < (G << 5)) out[tid] /= fmaxf(gcnt[tid >> 5], 1.0f);
}

extern "C" void kernel_launch(void* const* d_in, const int* in_sizes, int n_in,
                              void* d_out, int out_size, void* d_ws, size_t ws_size,
                              hipStream_t stream) {
    const float* x   = (const float*)d_in[0];
    const float* W1  = (const float*)d_in[1];
    const float* b1  = (const float*)d_in[2];
    const float* g1  = (const float*)d_in[3];
    const float* be1 = (const float*)d_in[4];
    const float* rm1 = (const float*)d_in[5];
    const float* rv1 = (const float*)d_in[6];
    const float* W2  = (const float*)d_in[7];
    const float* b2  = (const float*)d_in[8];
    const float* g2  = (const float*)d_in[9];
    const float* be2 = (const float*)d_in[10];
    const float* rm2 = (const float*)d_in[11];
    const float* rv2 = (const float*)d_in[12];
    const float* W3  = (const float*)d_in[13];
    const float* b3  = (const float*)d_in[14];
    const float* g3  = (const float*)d_in[15];
    const float* be3 = (const float*)d_in[16];
    const float* rm3 = (const float*)d_in[17];
    const float* rv3 = (const float*)d_in[18];
    const int* ei    = (const int*)d_in[19];
    const int* batch = (const int*)d_in[20];

    const int N = in_sizes[0] / 3;
    const int E = in_sizes[19] / 2;
    const int G = out_size / 32;
    const int* src = ei;
    const int* dst = ei + E;

    const int B = 256;
    const int nbins = (N + (1 << BINSHIFT) - 1) >> BINSHIFT;          // 196 for N=100k
    const int cap = (((E / nbins) * 3) / 2 + 15) & ~15;               // 1.5x mean
    const int STAGE_BLOCKS = 1024;
    const int chunk = (E + STAGE_BLOCKS - 1) / STAGE_BLOCKS;

    // workspace layout
    int*      gcur    = (int*)d_ws;                       // 256*GSTRIDE
    int*      binbase = gcur + 256 * GSTRIDE;             // 256
    int*      cnt     = binbase + 256;                    // N
    float*    dinv    = (float*)(cnt + N);                // N
    int*      rowptr  = (int*)(dinv + N);                 // N
    int*      eidx    = rowptr + N;                       // E
    float4*   xs      = (float4*)(((uintptr_t)(eidx + E) + 15) & ~(uintptr_t)15);  // N
    uint32_t* Tp      = (uint32_t*)(xs + N);              // N*32
    float*    hbuf    = (float*)(Tp + (size_t)N * 32);    // N*64
    float*    gcnt    = hbuf + (size_t)N * 64;            // G
    int2*     staged  = (int2*)hbuf;                      // alias: dead before hbuf written
    float*    out     = (float*)d_out;

    // ---- CSR build: multisplit stage -> bin scan -> per-bin fill ----
    hipMemsetAsync(gcur, 0, 256 * GSTRIDE * 4, stream);
    stage_ms_kernel<<<STAGE_BLOCKS, 256, 0, stream>>>(src, dst, gcur, staged, cap, nbins, E, chunk);
    binscan_kernel<<<1, 256, 0, stream>>>(gcur, binbase, nbins, out, gcnt, G);
    fill_csr_kernel<<<nbins, 256, 0, stream>>>(staged, binbase, gcur, x, cap,
                                               rowptr, cnt, dinv, xs, eidx, N);

    // ---- layer 1 fused: gather + GEMM(3->64) + BN ----
    layer1_kernel<<<(N + 7) / 8, 256, 0, stream>>>(xs, rowptr, cnt, eidx, dinv,
                                                   W1, b1, g1, be1, rm1, rv1, hbuf, N);

    // ---- layer 2 ----
    gemm_pack_scale_kernel<64, 64><<<(N + 7) / 8, 256, 0, stream>>>(hbuf, W2, dinv, Tp, N);
    gather_fuse_kernel<64><<<(int)(((size_t)N * 32 + B - 1) / B), B, 0, stream>>>(
        Tp, rowptr, cnt, eidx, dinv, b2, g2, be2, rm2, rv2, hbuf, N);

    // ---- layer 3 ----
    gemm_pack_scale_kernel<64, 32><<<(N + 15) / 16, 256, 0, stream>>>(hbuf, W3, dinv, Tp, N);
    gather_fuse_kernel<32><<<(int)(((size_t)N * 16 + B - 1) / B), B, 0, stream>>>(
        Tp, rowptr, cnt, eidx, dinv, b3, g3, be3, rm3, rv3, hbuf, N);

    // ---- mean pool ----
    pool_kernel2<<<(N + POOL_ROWS - 1) / POOL_ROWS, 256, 0, stream>>>(hbuf, batch, out, gcnt, N);
    pool_div_kernel<<<(G * 32 + B - 1) / B, B, 0, stream>>>(out, gcnt, G);
}

// Round 9
// 305.469 us; speedup vs baseline: 1.4938x; 1.1708x over previous
//
#include <hip/hip_runtime.h>

#define EPS_BN 1e-5f
#define NEG_SLOPE 0.01f

#define BINSHIFT 9                 // 512 nodes per bin
#define NBINS_LDS 200              // supports N up to 102400
#define BUFCAP 24                  // LDS records per (block,bin)
#define GSTRIDE 16                 // gcur padding: one counter per 64B line

// ---- bf16x2 pack/unpack (RNE) ----
__device__ __forceinline__ uint32_t pack2_bf16(float x, float y) {
    uint32_t ux = __float_as_uint(x);
    uint32_t uy = __float_as_uint(y);
    ux = (ux + 0x7fffu + ((ux >> 16) & 1u)) >> 16;
    uy = (uy + 0x7fffu + ((uy >> 16) & 1u)) >> 16;
    return (uy << 16) | (ux & 0xffffu);
}
__device__ __forceinline__ float bf_lo(uint32_t p) { return __uint_as_float(p << 16); }
__device__ __forceinline__ float bf_hi(uint32_t p) { return __uint_as_float(p & 0xffff0000u); }

// ---- phase A: LDS multisplit; 4 edges/thread/iter; pipelined drain atomics ----
__global__ void stage_ms_kernel(const int* __restrict__ src, const int* __restrict__ dst,
                                int* __restrict__ gcur, int2* __restrict__ staged,
                                int cap, int nbins, int E, int chunk) {
    __shared__ int2 bbuf[NBINS_LDS][BUFCAP];
    __shared__ int bcnt[NBINS_LDS];
    __shared__ int gpos[NBINS_LDS];
    for (int i = threadIdx.x; i < nbins; i += 256) bcnt[i] = 0;
    __syncthreads();
    int e0 = blockIdx.x * chunk;
    int e1 = min(e0 + chunk, E);
    for (int base = e0; base < e1; base += 1024) {       // 256 threads x 4 edges
        int e = base + threadIdx.x * 4;
        int s0, s1, s2, s3, d0, d1, d2, d3;
        int ne = 0;
        if (e + 4 <= e1) {
            int4 s4 = *(const int4*)(src + e);
            int4 d4 = *(const int4*)(dst + e);
            s0 = s4.x; s1 = s4.y; s2 = s4.z; s3 = s4.w;
            d0 = d4.x; d1 = d4.y; d2 = d4.z; d3 = d4.w;
            ne = 4;
        } else {
            int k = 0;
            for (; e + k < e1 && k < 4; ++k) {
                int sv = src[e + k], dv = dst[e + k];
                if (k == 0) { s0 = sv; d0 = dv; }
                else if (k == 1) { s1 = sv; d1 = dv; }
                else if (k == 2) { s2 = sv; d2 = dv; }
                else { s3 = sv; d3 = dv; }
            }
            ne = k;
        }
        #pragma unroll
        for (int k = 0; k < 4; ++k) {
            if (k >= ne) break;
            int s = (k == 0) ? s0 : (k == 1) ? s1 : (k == 2) ? s2 : s3;
            int d = (k == 0) ? d0 : (k == 1) ? d1 : (k == 2) ? d2 : d3;
            int bin = d >> BINSHIFT;
            int pos = atomicAdd(&bcnt[bin], 1);
            if (pos < BUFCAP) {
                bbuf[bin][pos] = make_int2(s, d);
            } else {                                     // rare: direct global append
                int gp = atomicAdd(&gcur[bin * GSTRIDE], 1);
                staged[(size_t)bin * cap + gp] = make_int2(s, d);
            }
        }
    }
    __syncthreads();
    // drain phase 1: one bin per THREAD -> all global atomics issue concurrently
    for (int b = threadIdx.x; b < nbins; b += 256) {
        int c = min(bcnt[b], BUFCAP);
        gpos[b] = (c > 0) ? atomicAdd(&gcur[b * GSTRIDE], c) : 0;
    }
    __syncthreads();
    // drain phase 2: cooperative 16-lane copy per bin
    int grp = threadIdx.x >> 4, lane = threadIdx.x & 15;
    for (int b = grp; b < nbins; b += 16) {
        int c = min(bcnt[b], BUFCAP);
        int gp = gpos[b];
        for (int i = lane; i < c; i += 16)
            staged[(size_t)b * cap + gp + i] = bbuf[b][i];
    }
}

// ---- exclusive scan of per-bin counts -> binbase; also zeros out/gcnt ----
__global__ void binscan_kernel(const int* __restrict__ gcur, int* __restrict__ binbase,
                               int nbins, float* __restrict__ out, float* __restrict__ gcnt,
                               int G) {
    __shared__ int s[256];
    int v = (threadIdx.x < nbins) ? gcur[threadIdx.x * GSTRIDE] : 0;
    s[threadIdx.x] = v;
    __syncthreads();
    for (int off = 1; off < 256; off <<= 1) {
        int t = (threadIdx.x >= off) ? s[threadIdx.x - off] : 0;
        __syncthreads();
        s[threadIdx.x] += t;
        __syncthreads();
    }
    if (threadIdx.x < nbins) binbase[threadIdx.x] = s[threadIdx.x] - v;
    for (int i = threadIdx.x; i < G * 32; i += 256) out[i] = 0.f;
    for (int i = threadIdx.x; i < G; i += 256) gcnt[i] = 0.f;
}

// ---- phase B: per-bin CSR fill + rowptr/cnt/dinv/xs; parallel in-bin scan ----
__global__ void fill_csr_kernel(const int2* __restrict__ staged, const int* __restrict__ binbase,
                                const int* __restrict__ gcur, const float* __restrict__ x,
                                int cap, int* __restrict__ rowptr, int* __restrict__ cnt,
                                float* __restrict__ dinv, float4* __restrict__ xs,
                                int* __restrict__ eidx, int N) {
    __shared__ int lcnt[1 << BINSHIFT];
    __shared__ int loff[1 << BINSHIFT];
    __shared__ int ps[256];
    int bin = blockIdx.x;
    int node0 = bin << BINSHIFT;
    int nn = min(1 << BINSHIFT, N - node0);
    int nrec = gcur[bin * GSTRIDE];
    const int2* recs = staged + (size_t)bin * cap;
    for (int i = threadIdx.x; i < (1 << BINSHIFT); i += 256) lcnt[i] = 0;
    __syncthreads();
    for (int t = threadIdx.x; t < nrec; t += 256) atomicAdd(&lcnt[recs[t].y - node0], 1);
    __syncthreads();
    int p0 = lcnt[2 * threadIdx.x], p1 = lcnt[2 * threadIdx.x + 1];
    int pv = p0 + p1;
    ps[threadIdx.x] = pv;
    __syncthreads();
    for (int off = 1; off < 256; off <<= 1) {
        int t = (threadIdx.x >= off) ? ps[threadIdx.x - off] : 0;
        __syncthreads();
        ps[threadIdx.x] += t;
        __syncthreads();
    }
    int base = ps[threadIdx.x] - pv;
    loff[2 * threadIdx.x] = base;
    loff[2 * threadIdx.x + 1] = base + p0;
    __syncthreads();
    int bb = binbase[bin];
    for (int i = threadIdx.x; i < nn; i += 256) {
        int node = node0 + i;
        rowptr[node] = bb + loff[i];
        cnt[node] = lcnt[i];
        float di = rsqrtf((float)(lcnt[i] + 1));         // +1 self-loop
        dinv[node] = di;
        const float* xr = x + (size_t)node * 3;
        xs[node] = make_float4(xr[0] * di, xr[1] * di, xr[2] * di, 0.f);
        lcnt[i] = 0;                                     // reuse as cursor
    }
    __syncthreads();
    for (int t = threadIdx.x; t < nrec; t += 256) {
        int2 r = recs[t];
        int li = r.y - node0;
        int p = atomicAdd(&lcnt[li], 1);
        eidx[bb + loff[li] + p] = r.x;                   // block-private range
    }
}

// ---- fused layer 1: gather xs + (3->64 GEMM) + bias + BN + LeakyReLU ----
__global__ void layer1_kernel(const float4* __restrict__ xs, const int* __restrict__ rowptr,
                              const int* __restrict__ cnt, const int* __restrict__ eidx,
                              const float* __restrict__ dinv, const float* __restrict__ W,
                              const float* __restrict__ b, const float* __restrict__ gamma,
                              const float* __restrict__ beta, const float* __restrict__ rm,
                              const float* __restrict__ rv, float* __restrict__ h, int N) {
    __shared__ float sW[3 * 64];
    __shared__ float sScale[64], sShift[64];
    if (threadIdx.x < 3 * 64) sW[threadIdx.x] = W[threadIdx.x];
    if (threadIdx.x < 64) {
        int f = threadIdx.x;
        float sc = rsqrtf(rv[f] + EPS_BN) * gamma[f];
        sScale[f] = sc;
        sShift[f] = (b[f] - rm[f]) * sc + beta[f];
    }
    __syncthreads();
    int node = blockIdx.x * 8 + (int)(threadIdx.x >> 5);
    if (node >= N) return;
    int lane = threadIdx.x & 31;
    int start = rowptr[node], deg = cnt[node];
    float ax = 0.f, ay = 0.f, az = 0.f;
    for (int j = lane; j < deg; j += 32) {
        float4 v = xs[eidx[start + j]];
        ax += v.x; ay += v.y; az += v.z;
    }
    for (int o = 16; o; o >>= 1) {
        ax += __shfl_down(ax, o, 32);
        ay += __shfl_down(ay, o, 32);
        az += __shfl_down(az, o, 32);
    }
    ax = __shfl(ax, 0, 32); ay = __shfl(ay, 0, 32); az = __shfl(az, 0, 32);
    float4 self = xs[node];
    float di = dinv[node];
    float gx = (ax + self.x) * di, gy = (ay + self.y) * di, gz = (az + self.z) * di;
    int f0 = lane * 2, f1 = f0 + 1;
    float a0 = gx * sW[f0] + gy * sW[64 + f0] + gz * sW[128 + f0];
    float a1 = gx * sW[f1] + gy * sW[64 + f1] + gz * sW[128 + f1];
    float y0 = a0 * sScale[f0] + sShift[f0];
    float y1 = a1 * sScale[f1] + sShift[f1];
    float2 o2;
    o2.x = (y0 >= 0.f) ? y0 : NEG_SLOPE * y0;
    o2.y = (y1 >= 0.f) ? y1 : NEG_SLOPE * y1;
    *(float2*)(h + (size_t)node * 64 + f0) = o2;
}

// ---- dense GEMM + dinv row-scale + bf16 pack: Tp[n] = (H[n]@W)*dinv[n] ----
template <int FIN, int FOUT>
__global__ void gemm_pack_scale_kernel(const float* __restrict__ H, const float* __restrict__ W,
                                       const float* __restrict__ dinv, uint32_t* __restrict__ Tp,
                                       int N) {
    constexpr int TPN = FOUT / 2;
    constexpr int NPB = 256 / TPN;
    __shared__ float sW[FIN * FOUT];
    for (int i = threadIdx.x; i < FIN * FOUT; i += 256) sW[i] = W[i];
    __syncthreads();
    int node = blockIdx.x * NPB + (int)(threadIdx.x / TPN);
    int f2 = threadIdx.x % TPN;
    if (node >= N) return;
    const float* h = H + (size_t)node * FIN;
    const float2* w2 = (const float2*)sW + f2;
    float a0 = 0.f, a1 = 0.f;
    for (int k = 0; k + 4 <= FIN; k += 4) {
        float4 hv = *(const float4*)(h + k);
        float2 w;
        w = w2[(k + 0) * TPN]; a0 = fmaf(hv.x, w.x, a0); a1 = fmaf(hv.x, w.y, a1);
        w = w2[(k + 1) * TPN]; a0 = fmaf(hv.y, w.x, a0); a1 = fmaf(hv.y, w.y, a1);
        w = w2[(k + 2) * TPN]; a0 = fmaf(hv.z, w.x, a0); a1 = fmaf(hv.z, w.y, a1);
        w = w2[(k + 3) * TPN]; a0 = fmaf(hv.w, w.x, a0); a1 = fmaf(hv.w, w.y, a1);
    }
    float di = dinv[node];
    Tp[(size_t)node * TPN + f2] = pack2_bf16(a0 * di, a1 * di);
}

// ---- CSR gather (scaled bf16 rows, 4B records) + BN + LeakyReLU; 4-way ILP ----
template <int F>
__global__ void gather_fuse_kernel(const uint32_t* __restrict__ Tp, const int* __restrict__ rowptr,
                                   const int* __restrict__ cnt, const int* __restrict__ eidx,
                                   const float* __restrict__ dinv,
                                   const float* __restrict__ b, const float* __restrict__ gamma,
                                   const float* __restrict__ beta, const float* __restrict__ rm,
                                   const float* __restrict__ rv,
                                   float* __restrict__ h, int N) {
    constexpr int TPN = F / 2;
    int tid = blockIdx.x * blockDim.x + threadIdx.x;
    int node = tid / TPN;
    if (node >= N) return;
    int f2 = tid % TPN;
    int start = rowptr[node];
    int deg = cnt[node];
    uint32_t tself = Tp[(size_t)node * TPN + f2];
    float a0 = bf_lo(tself), a1 = bf_hi(tself);
    float c0 = 0.f, c1 = 0.f;
    const int* ep = eidx + start;
    int j = 0;
    for (; j + 4 <= deg; j += 4) {
        int s0 = ep[j], s1 = ep[j + 1], s2 = ep[j + 2], s3 = ep[j + 3];
        uint32_t t0 = Tp[(size_t)s0 * TPN + f2];
        uint32_t t1 = Tp[(size_t)s1 * TPN + f2];
        uint32_t t2 = Tp[(size_t)s2 * TPN + f2];
        uint32_t t3 = Tp[(size_t)s3 * TPN + f2];
        a0 += bf_lo(t0) + bf_lo(t2);
        a1 += bf_hi(t0) + bf_hi(t2);
        c0 += bf_lo(t1) + bf_lo(t3);
        c1 += bf_hi(t1) + bf_hi(t3);
    }
    for (; j < deg; ++j) {
        uint32_t t0 = Tp[(size_t)ep[j] * TPN + f2];
        a0 += bf_lo(t0); a1 += bf_hi(t0);
    }
    float di = dinv[node];
    int f0 = 2 * f2, f1 = f0 + 1;
    float sc0 = rsqrtf(rv[f0] + EPS_BN) * gamma[f0];
    float sc1 = rsqrtf(rv[f1] + EPS_BN) * gamma[f1];
    float y0 = (a0 + c0) * di * sc0 + (b[f0] - rm[f0]) * sc0 + beta[f0];
    float y1 = (a1 + c1) * di * sc1 + (b[f1] - rm[f1]) * sc1 + beta[f1];
    float2 o;
    o.x = (y0 >= 0.f) ? y0 : NEG_SLOPE * y0;
    o.y = (y1 >= 0.f) ? y1 : NEG_SLOPE * y1;
    *(float2*)(h + (size_t)node * F + f0) = o;
}

// ---- mean pool: batch sorted -> register-accumulate, flush on graph change ----
#define POOL_ROWS 128
__global__ void pool_kernel2(const float* __restrict__ h, const int* __restrict__ batch,
                             float* __restrict__ out, float* __restrict__ gcnt, int N) {
    int f = threadIdx.x & 31;
    int rg = threadIdx.x >> 5;
    int n0 = blockIdx.x * POOL_ROWS;
    float acc = 0.f;
    int cnt = 0, gcur = -1;
    for (int r = rg; r < POOL_ROWS; r += 8) {
        int node = n0 + r;
        if (node >= N) break;
        int g = batch[node];
        if (g != gcur) {
            if (gcur >= 0) {
                atomicAdd(&out[(gcur << 5) + f], acc);
                if (f == 0) atomicAdd(&gcnt[gcur], (float)cnt);
            }
            gcur = g; acc = 0.f; cnt = 0;
        }
        acc += h[(size_t)node * 32 + f];
        cnt++;
    }
    if (gcur >= 0) {
        atomicAdd(&out[(gcur << 5) + f], acc);
        if (f == 0) atomicAdd(&gcnt[gcur], (float)cnt);
    }
}

__global__ void pool_div_kernel(float* __restrict__ out, const float* __restrict__ gcnt, int G) {
    int tid = blockIdx.x * blockDim.x + threadIdx.x;
    if (tid < (G << 5)) out[tid] /= fmaxf(gcnt[tid >> 5], 1.0f);
}

extern "C" void kernel_launch(void* const* d_in, const int* in_sizes, int n_in,
                              void* d_out, int out_size, void* d_ws, size_t ws_size,
                              hipStream_t stream) {
    const float* x   = (const float*)d_in[0];
    const float* W1  = (const float*)d_in[1];
    const float* b1  = (const float*)d_in[2];
    const float* g1  = (const float*)d_in[3];
    const float* be1 = (const float*)d_in[4];
    const float* rm1 = (const float*)d_in[5];
    const float* rv1 = (const float*)d_in[6];
    const float* W2  = (const float*)d_in[7];
    const float* b2  = (const float*)d_in[8];
    const float* g2  = (const float*)d_in[9];
    const float* be2 = (const float*)d_in[10];
    const float* rm2 = (const float*)d_in[11];
    const float* rv2 = (const float*)d_in[12];
    const float* W3  = (const float*)d_in[13];
    const float* b3  = (const float*)d_in[14];
    const float* g3  = (const float*)d_in[15];
    const float* be3 = (const float*)d_in[16];
    const float* rm3 = (const float*)d_in[17];
    const float* rv3 = (const float*)d_in[18];
    const int* ei    = (const int*)d_in[19];
    const int* batch = (const int*)d_in[20];

    const int N = in_sizes[0] / 3;
    const int E = in_sizes[19] / 2;
    const int G = out_size / 32;
    const int* src = ei;
    const int* dst = ei + E;

    const int B = 256;
    const int nbins = (N + (1 << BINSHIFT) - 1) >> BINSHIFT;          // 196 for N=100k
    const int cap = (((E / nbins) * 3) / 2 + 15) & ~15;               // 1.5x mean
    const int STAGE_BLOCKS = 512;
    const int chunk = (((E + STAGE_BLOCKS - 1) / STAGE_BLOCKS) + 3) & ~3;  // 4-aligned

    // workspace layout
    int*      gcur    = (int*)d_ws;                       // 256*GSTRIDE
    int*      binbase = gcur + 256 * GSTRIDE;             // 256
    int*      cnt     = binbase + 256;                    // N
    float*    dinv    = (float*)(cnt + N);                // N
    int*      rowptr  = (int*)(dinv + N);                 // N
    int*      eidx    = rowptr + N;                       // E
    float4*   xs      = (float4*)(((uintptr_t)(eidx + E) + 15) & ~(uintptr_t)15);  // N
    uint32_t* Tp      = (uint32_t*)(xs + N);              // N*32
    float*    hbuf    = (float*)(Tp + (size_t)N * 32);    // N*64
    float*    gcnt    = hbuf + (size_t)N * 64;            // G
    int2*     staged  = (int2*)hbuf;                      // alias: dead before hbuf written
    float*    out     = (float*)d_out;

    // ---- CSR build: multisplit stage -> bin scan -> per-bin fill ----
    hipMemsetAsync(gcur, 0, 256 * GSTRIDE * 4, stream);
    stage_ms_kernel<<<STAGE_BLOCKS, 256, 0, stream>>>(src, dst, gcur, staged, cap, nbins, E, chunk);
    binscan_kernel<<<1, 256, 0, stream>>>(gcur, binbase, nbins, out, gcnt, G);
    fill_csr_kernel<<<nbins, 256, 0, stream>>>(staged, binbase, gcur, x, cap,
                                               rowptr, cnt, dinv, xs, eidx, N);

    // ---- layer 1 fused: gather + GEMM(3->64) + BN ----
    layer1_kernel<<<(N + 7) / 8, 256, 0, stream>>>(xs, rowptr, cnt, eidx, dinv,
                                                   W1, b1, g1, be1, rm1, rv1, hbuf, N);

    // ---- layer 2 ----
    gemm_pack_scale_kernel<64, 64><<<(N + 7) / 8, 256, 0, stream>>>(hbuf, W2, dinv, Tp, N);
    gather_fuse_kernel<64><<<(int)(((size_t)N * 32 + B - 1) / B), B, 0, stream>>>(
        Tp, rowptr, cnt, eidx, dinv, b2, g2, be2, rm2, rv2, hbuf, N);

    // ---- layer 3 ----
    gemm_pack_scale_kernel<64, 32><<<(N + 15) / 16, 256, 0, stream>>>(hbuf, W3, dinv, Tp, N);
    gather_fuse_kernel<32><<<(int)(((size_t)N * 16 + B - 1) / B), B, 0, stream>>>(
        Tp, rowptr, cnt, eidx, dinv, b3, g3, be3, rm3, rv3, hbuf, N);

    // ---- mean pool ----
    pool_kernel2<<<(N + POOL_ROWS - 1) / POOL_ROWS, 256, 0, stream>>>(hbuf, batch, out, gcnt, N);
    pool_div_kernel<<<(G * 32 + B - 1) / B, B, 0, stream>>>(out, gcnt, G);
}